// Round 10
// baseline (1489.432 us; speedup 1.0000x reference)
//
#include <hip/hip_runtime.h>

// ---------------------------------------------------------------------------
// MPN (chemprop) on MI355X. bf16 MFMA (16x16x32), fp32 accum.
//   relu(inp + m@W_h) == relu([f_bonds | m] @ [W_i ; W_h])  -> no stored inp.
//   combine (a_msg[b2a[b]] - msg[b2revb[b]]) fused into GEMM A-staging.
// R1: XCD-paired decode. R2: de-fuse REVERTED. R3: depth-2 + counted barrier.
// R4: all-direct frags REVERTED. R5/R6: A LDS-staged, B direct from
//     fragment-linear Wf. R7: 4 waves/SIMD REVERTED (2x occupancy, +27% dur).
// R9: deferred bfsub REVERTED (+28 VGPR -> occupancy 10.6%, +27% dur).
// R10: BARRIER-FREE GEMM. Seven variants all pinned at 12-16% MfmaUtil with
//     one shared feature: a 4-wave s_barrier every kt. Now the A-tile is
//     WAVE-PRIVATE (each wave stages its own 64 fragment rows; lane<->row
//     1:1, 4x16B chunks, XOR-quarter swizzle) -> zero cross-wave deps ->
//     ALL barriers deleted. 8 resident waves/CU free-run as independent
//     pipelines; compiler emits per-wave counted waits only. Cost: A read
//     2x per block (wn-pair duplication, L2-absorbed).
// GEMM: block 128M x 160N, wave 64x80 (4x5), depth-2 P/Q prefetch.
// Workspace (~367 MiB): wih | wto | fbp | amsg | msgA | msgB
// ---------------------------------------------------------------------------

#define DEVFN static __device__ __forceinline__

typedef __attribute__((ext_vector_type(8))) __bf16 bf16x8;
typedef __attribute__((ext_vector_type(4))) float floatx4;

DEVFN unsigned short f2bf(float f) {
    unsigned int u = __float_as_uint(f);
    u += 0x7FFFu + ((u >> 16) & 1u);   // RNE
    return (unsigned short)(u >> 16);
}
DEVFN float bf2f(unsigned int u) { return __uint_as_float(u << 16); }

// packed bf16x2 subtract via fp32 (exact in fp32, RNE back)
DEVFN unsigned int bfsub2(unsigned int a, unsigned int m) {
    float lo = bf2f(a & 0xffffu) - bf2f(m & 0xffffu);
    float hi = bf2f(a >> 16) - bf2f(m >> 16);
    return (unsigned int)f2bf(lo) | ((unsigned int)f2bf(hi) << 16);
}
DEVFN uint4 bfsub8(uint4 a, uint4 m) {
    return make_uint4(bfsub2(a.x, m.x), bfsub2(a.y, m.y),
                      bfsub2(a.z, m.z), bfsub2(a.w, m.w));
}

// ---------------------------------------------------------------------------
__global__ __launch_bounds__(256) void dbg_fill(float* out, int n, float v) {
    int t = blockIdx.x * 256 + threadIdx.x;
    if (t < n) out[t] = v;
}

// W -> fragment-linear layout: Wf[((nb*KTS + kt)*64 + lane)*8 + j]
//   element (n,k): n = nb*16 + (lane&15), k = kt*32 + (lane>>4)*8 + j.
// Wih (KTS=15, K=480): k<147 -> W_i[k][n]; 160<=k<460 -> W_h[k-160][n]; else 0
__global__ __launch_bounds__(256) void prep_wih(const float* __restrict__ Wi,
                                                const float* __restrict__ Wh,
                                                unsigned short* __restrict__ Wt) {
    int t = blockIdx.x * 256 + threadIdx.x;
    if (t >= 320 * 480) return;
    int j = t & 7;
    int lane = (t >> 3) & 63;
    int rest = t >> 9;                 // nb*15 + kt
    int kt = rest % 15, nb = rest / 15;
    int n = nb * 16 + (lane & 15);
    int k = kt * 32 + (lane >> 4) * 8 + j;
    float v = 0.f;
    if (n < 300) {
        if (k < 147) v = Wi[k * 300 + n];
        else if (k >= 160 && k < 460) v = Wh[(k - 160) * 300 + n];
    }
    Wt[t] = f2bf(v);
}

// Wto (KTS=14, K=448): k<300 -> W_o[133+k][n]; 304<=k<437 -> W_o[k-304][n]
__global__ __launch_bounds__(256) void prep_wto(const float* __restrict__ Wo,
                                                unsigned short* __restrict__ Wt) {
    int t = blockIdx.x * 256 + threadIdx.x;
    if (t >= 320 * 448) return;
    int j = t & 7;
    int lane = (t >> 3) & 63;
    int rest = t >> 9;                 // nb*14 + kt
    int kt = rest % 14, nb = rest / 14;
    int n = nb * 16 + (lane & 15);
    int k = kt * 32 + (lane >> 4) * 8 + j;
    float v = 0.f;
    if (n < 300) {
        if (k < 300) v = Wo[(133 + k) * 300 + n];
        else if (k >= 304 && k < 437) v = Wo[(k - 304) * 300 + n];
    }
    Wt[t] = f2bf(v);
}

// f_bonds [200000][147] fp32 -> [200000][160] bf16 padded
__global__ __launch_bounds__(256) void pad_bonds(const float* __restrict__ fb,
                                                 unsigned short* __restrict__ out) {
    int t = blockIdx.x * 256 + threadIdx.x;
    if (t >= 200000 * 20) return;
    int b = t / 20, c = t - b * 20;
    unsigned int o[4];
#pragma unroll
    for (int p = 0; p < 4; ++p) {
        int sc = c * 8 + p * 2;
        float v0 = (sc < 147) ? fb[(size_t)b * 147 + sc] : 0.f;
        float v1 = (sc + 1 < 147) ? fb[(size_t)b * 147 + sc + 1] : 0.f;
        o[p] = (unsigned int)f2bf(v0) | ((unsigned int)f2bf(v1) << 16);
    }
    *(uint4*)(out + (size_t)b * 160 + c * 8) = make_uint4(o[0], o[1], o[2], o[3]);
}

// f_atoms [100000][133] fp32 -> concat cols 304..447
__global__ __launch_bounds__(256) void atoms_concat(const float* __restrict__ fa,
                                                    unsigned short* __restrict__ concat) {
    int t = blockIdx.x * 256 + threadIdx.x;
    if (t >= 100000 * 18) return;
    int a = t / 18, c = t - a * 18;
    unsigned int o[4];
#pragma unroll
    for (int p = 0; p < 4; ++p) {
        int sc = c * 8 + p * 2;
        float v0 = (sc < 133) ? fa[(size_t)a * 133 + sc] : 0.f;
        float v1 = (sc + 1 < 133) ? fa[(size_t)a * 133 + sc + 1] : 0.f;
        o[p] = (unsigned int)f2bf(v0) | ((unsigned int)f2bf(v1) << 16);
    }
    *(uint4*)(concat + (size_t)a * 448 + 304 + c * 8) = make_uint4(o[0], o[1], o[2], o[3]);
}

// a_msg[a] = sum_j msg[a2b[a][j]]
template <int CH>
__global__ __launch_bounds__(256) void gather_sum(const unsigned short* __restrict__ msg,
                                                  const int* __restrict__ a2b,
                                                  unsigned short* __restrict__ out,
                                                  int ostride, int nA) {
    int t = blockIdx.x * 256 + threadIdx.x;
    if (t >= nA * CH) return;
    int a = t / CH, c = t - a * CH;
    float s[8] = {0, 0, 0, 0, 0, 0, 0, 0};
#pragma unroll
    for (int j = 0; j < 6; ++j) {
        int b = a2b[a * 6 + j];
        uint4 v = *(const uint4*)(msg + (size_t)b * 320 + c * 8);
        s[0] += bf2f(v.x & 0xffffu); s[1] += bf2f(v.x >> 16);
        s[2] += bf2f(v.y & 0xffffu); s[3] += bf2f(v.y >> 16);
        s[4] += bf2f(v.z & 0xffffu); s[5] += bf2f(v.z >> 16);
        s[6] += bf2f(v.w & 0xffffu); s[7] += bf2f(v.w >> 16);
    }
    unsigned int o[4];
#pragma unroll
    for (int p = 0; p < 4; ++p)
        o[p] = (unsigned int)f2bf(s[2 * p]) | ((unsigned int)f2bf(s[2 * p + 1]) << 16);
    *(uint4*)(out + (size_t)a * ostride + c * 8) = make_uint4(o[0], o[1], o[2], o[3]);
}

// ---------------------------------------------------------------------------
// Barrier-free hybrid GEMM.  C[M][320] = [A0 | combine] @ W^T
//   A: WAVE-PRIVATE LDS staging. Lane l owns global row (m0 + wm*64 + l);
//      per kt it loads the 64B k-slice as 4x16B chunks (chunk c stored at
//      c ^ (l&3) -> conflict-spread) into its wave's private region. No
//      cross-wave sharing -> NO BARRIERS anywhere in the kernel.
//   B: fragment-linear Wf, one contiguous 1KB global load per (tn,kt) into
//      MFMA operand regs (no LDS). Wf nb-stride = WNB*512 shorts.
//   Block: 128M x 160N; 4 waves 2x2; wave 64x80 (4 tm x 5 tn).
//   Grid: 1-D, 2*MB blocks, XCD-paired decode.
//   K = (KT0+KT1)*32. kt<KT0: A from A0 (stride a0s). kt>=KT0 (hidden only):
//   A row r = bf16(amsg[b2a[r]] - msg[b2revb[r]]), subtract at load time
//   (stalls only this wave; 7 other resident waves keep issuing).
//   Depth-2 P/Q register sets; per iter: compute(kt) -> ldg(kt+2) ->
//   stw(kt+1). Compiler inserts per-wave counted vm/lgkm waits only.
// MODE 0: outp[r*320+col] = relu(acc) bf16
// MODE 2: hid[r*300+col]  = relu(acc + bo[col]) fp32  (col<300)
// LDS: As[4 waves][2 bufs][64 rows][40 shorts] = 40 KiB.
// ---------------------------------------------------------------------------
template <int KT0, int KT1, int MODE, int WNB>
__global__ __launch_bounds__(256) void gemm_k(const unsigned short* __restrict__ A0,
                                              int a0s,
                                              const unsigned short* __restrict__ amsg,
                                              const unsigned short* __restrict__ msg,
                                              const int* __restrict__ b2a,
                                              const int* __restrict__ b2revb,
                                              const unsigned short* __restrict__ Wf,
                                              unsigned short* __restrict__ outp,
                                              float* __restrict__ hid,
                                              const float* __restrict__ bo, int M) {
    constexpr int KT = KT0 + KT1;
    __shared__ unsigned short As[4 * 2 * 2560];   // [wave][buf][64][40]

    const int tid = threadIdx.x;
    const int lane = tid & 63;
    const int wave = tid >> 6;
    const int wm = wave & 1, wn = wave >> 1;
    const int l16 = lane & 15, quad = lane >> 4;

    // ---- XCD-paired m/n decode (bijective incl. tail) ----
    int m0, n0;
    {
        const int bid = blockIdx.x;
        const int MB = (int)(gridDim.x >> 1);
        const int mfull = (MB >> 3) << 3;        // largest mult of 8 <= MB
        const int FULL = mfull << 1;
        int mb, nh;
        if (bid < FULL) {
            nh = (bid >> 3) & 1;
            mb = ((bid >> 4) << 3) + (bid & 7);
        } else {
            const int r = bid - FULL;
            const int rem = MB - mfull;
            nh = (r >= rem) ? 1 : 0;
            mb = mfull + r - nh * rem;
        }
        m0 = mb * 128;
        n0 = nh * 160;
    }

    // ---- A staging: lane owns one row of this wave's 64-row half ----
    const int ar = min(m0 + wm * 64 + lane, M - 1);
    const unsigned short* a0p = A0 + (size_t)ar * a0s;
    const unsigned short* a1p = nullptr;
    const unsigned short* m1p = nullptr;
    if (KT1 > 0) {
        a1p = amsg + (size_t)b2a[ar] * 320;
        m1p = msg + (size_t)b2revb[ar] * 320;
    }
    unsigned short* myAs = As + wave * 5120;          // private [2][64][40]

    // ---- B fragment pointers (fragment-linear Wf; contiguous 1KB/load) ----
    const int nbase = (n0 >> 4) + wn * 5;
    const unsigned short* pB[5];
#pragma unroll
    for (int tn = 0; tn < 5; ++tn)
        pB[tn] = Wf + (size_t)(nbase + tn) * (WNB * 512) + lane * 8;

    // ---- A fragment LDS offsets (XOR-quarter swizzled chunks) ----
    int aoff[4];
#pragma unroll
    for (int tm = 0; tm < 4; ++tm)
        aoff[tm] = (tm * 16 + l16) * 40 + ((quad ^ (l16 & 3)) * 8);

    floatx4 acc[4][5];
#pragma unroll
    for (int tm = 0; tm < 4; ++tm)
#pragma unroll
        for (int tn = 0; tn < 5; ++tn) acc[tm][tn] = (floatx4){0.f, 0.f, 0.f, 0.f};

    // ---- depth-2 register sets ----
    struct Set { uint4 a[4]; uint4 b[5]; };
    Set P, Q;

    auto ldg = [&](int kt, Set& s) {
        if (kt < KT0) {
#pragma unroll
            for (int c = 0; c < 4; ++c)
                s.a[c] = *(const uint4*)(a0p + kt * 32 + c * 8);
        } else {
            const int ko = (kt - KT0) * 32;
#pragma unroll
            for (int c = 0; c < 4; ++c) {
                uint4 va = *(const uint4*)(a1p + ko + c * 8);
                uint4 vm = *(const uint4*)(m1p + ko + c * 8);
                s.a[c] = bfsub8(va, vm);
            }
        }
#pragma unroll
        for (int tn = 0; tn < 5; ++tn)
            s.b[tn] = *(const uint4*)(pB[tn] + kt * 512);
    };
    auto stw = [&](int buf, const Set& s) {
        unsigned short* ab = myAs + buf * 2560 + lane * 40;
#pragma unroll
        for (int c = 0; c < 4; ++c)
            *(uint4*)(ab + ((c ^ (lane & 3)) * 8)) = s.a[c];
    };
    auto compute = [&](int buf, const Set& s) {
        bf16x8 av[4];
#pragma unroll
        for (int tm = 0; tm < 4; ++tm)
            av[tm] = *(const bf16x8*)(myAs + buf * 2560 + aoff[tm]);
#pragma unroll
        for (int tn = 0; tn < 5; ++tn)
#pragma unroll
            for (int tm = 0; tm < 4; ++tm)
                acc[tm][tn] = __builtin_amdgcn_mfma_f32_16x16x32_bf16(
                    av[tm], __builtin_bit_cast(bf16x8, s.b[tn]), acc[tm][tn], 0, 0, 0);
    };

    // ---- prologue: kt0 -> P -> LDS[0]; kt1 -> Q (in flight) ----
    ldg(0, P);
    if (KT > 1) ldg(1, Q);
    stw(0, P);

#pragma unroll
    for (int kt = 0; kt < KT; ++kt) {
        const int buf = kt & 1;
        if ((kt & 1) == 0) {
            compute(buf, P);
            if (kt + 2 < KT) ldg(kt + 2, P);
            if (kt + 1 < KT) stw(buf ^ 1, Q);
        } else {
            compute(buf, Q);
            if (kt + 2 < KT) ldg(kt + 2, Q);
            if (kt + 1 < KT) stw(buf ^ 1, P);
        }
    }

    // ---- epilogue ----
    float bias[5];
    if (MODE == 2) {
#pragma unroll
        for (int tn = 0; tn < 5; ++tn) {
            int col = n0 + wn * 80 + tn * 16 + l16;
            bias[tn] = (col < 300) ? bo[col] : 0.f;
        }
    }
#pragma unroll
    for (int tm = 0; tm < 4; ++tm) {
        const int r0 = m0 + wm * 64 + tm * 16 + quad * 4;
#pragma unroll
        for (int tn = 0; tn < 5; ++tn) {
            const int col = n0 + wn * 80 + tn * 16 + l16;
#pragma unroll
            for (int i = 0; i < 4; ++i) {
                int r = r0 + i;
                if (r >= M) continue;
                float c = acc[tm][tn][i];
                if (MODE == 2) {
                    if (col < 300) hid[(size_t)r * 300 + col] = fmaxf(c + bias[tn], 0.f);
                } else {
                    outp[(size_t)r * 320 + col] = f2bf(fmaxf(c, 0.f));
                }
            }
        }
    }
}

// ---------------------------------------------------------------------------
// Per-molecule mean. mol_ids sorted -> binary search row range.
// ---------------------------------------------------------------------------
__global__ __launch_bounds__(320) void mean_k(const float* __restrict__ hid,
                                              const int* __restrict__ mol_ids,
                                              float* __restrict__ out, int nA) {
    int mol = blockIdx.x;
    int lo, hi;
    {
        int l = 0, h = nA;
        while (l < h) { int m = (l + h) >> 1; if (mol_ids[m] < mol) l = m + 1; else h = m; }
        lo = l;
    }
    {
        int l = lo, h = nA;
        while (l < h) { int m = (l + h) >> 1; if (mol_ids[m] < mol + 1) l = m + 1; else h = m; }
        hi = l;
    }
    int col = threadIdx.x;
    if (col >= 300) return;
    float s = 0.f;
    for (int a = lo; a < hi; ++a) s += hid[(size_t)a * 300 + col];
    int cnt = hi - lo;
    out[(size_t)mol * 300 + col] = s / (float)(cnt > 0 ? cnt : 1);
}

// ---------------------------------------------------------------------------
extern "C" void kernel_launch(void* const* d_in, const int* in_sizes, int n_in,
                              void* d_out, int out_size, void* d_ws, size_t ws_size,
                              hipStream_t stream) {
    (void)in_sizes; (void)n_in;
    const float* f_atoms = (const float*)d_in[0];
    const float* f_bonds = (const float*)d_in[1];
    const float* W_i     = (const float*)d_in[2];
    const float* W_h     = (const float*)d_in[3];
    const float* W_o     = (const float*)d_in[4];
    const float* b_o     = (const float*)d_in[5];
    const int*   a2b     = (const int*)d_in[6];
    const int*   b2a     = (const int*)d_in[7];
    const int*   b2revb  = (const int*)d_in[8];
    const int*   mol_ids = (const int*)d_in[9];

    const size_t sz_wih  = 320ull * 480 * 2;
    const size_t sz_wto  = 320ull * 448 * 2;
    const size_t sz_fbp  = 200000ull * 160 * 2;
    const size_t sz_amsg = 100000ull * 320 * 2;
    const size_t sz_msg  = 200000ull * 320 * 2;
    const size_t need = sz_wih + sz_wto + sz_fbp + sz_amsg + 2 * sz_msg;

    if (ws_size < need) {
        dbg_fill<<<(out_size + 255) / 256, 256, 0, stream>>>(
            (float*)d_out, out_size, (float)(ws_size >> 20));
        return;
    }

    char* ws = (char*)d_ws;
    unsigned short* wih  = (unsigned short*)(ws);
    unsigned short* wto  = (unsigned short*)(ws + sz_wih);
    unsigned short* fbp  = (unsigned short*)(ws + sz_wih + sz_wto);
    unsigned short* amsg = (unsigned short*)(ws + sz_wih + sz_wto + sz_fbp);
    unsigned short* msgA = (unsigned short*)(ws + sz_wih + sz_wto + sz_fbp + sz_amsg);
    unsigned short* msgB = (unsigned short*)(ws + sz_wih + sz_wto + sz_fbp + sz_amsg + sz_msg);
    unsigned short* concat = msgA;                     // msgA dead after loop
    float*          hid    = (float*)msgB;             // msgB dead after final gather

    prep_wih<<<600, 256, 0, stream>>>(W_i, W_h, wih);
    prep_wto<<<560, 256, 0, stream>>>(W_o, wto);
    pad_bonds<<<15625, 256, 0, stream>>>(f_bonds, fbp);

    // msgA = relu(f_bonds @ W_i)   (grid = 2*MB, MB = ceil(200000/128) = 1563)
    gemm_k<5, 0, 0, 15><<<dim3(3126), 256, 0, stream>>>(
        fbp, 160, nullptr, nullptr, nullptr, nullptr, wih, msgA, nullptr, nullptr, 200000);

    unsigned short* cur = msgA;
    unsigned short* other = msgB;
    for (int d = 0; d < 3; ++d) {   // DEPTH-1
        gather_sum<40><<<15625, 256, 0, stream>>>(cur, a2b, amsg, 320, 100000);
        gemm_k<5, 10, 0, 15><<<dim3(3126), 256, 0, stream>>>(
            fbp, 160, amsg, cur, b2a, b2revb, wih, other, nullptr, nullptr, 200000);
        unsigned short* t = cur; cur = other; other = t;
    }

    // final gather into concat cols 0..303 (cur == msgB; concat == msgA)
    gather_sum<38><<<14844, 256, 0, stream>>>(cur, a2b, concat, 448, 100000);
    atoms_concat<<<7032, 256, 0, stream>>>(f_atoms, concat);
    // hid = relu(concat @ W_o + b_o)   (MB = ceil(100000/128) = 782)
    gemm_k<14, 0, 2, 14><<<dim3(1564), 256, 0, stream>>>(
        concat, 448, nullptr, nullptr, nullptr, nullptr, wto, nullptr, hid, b_o, 100000);
    mean_k<<<8192, 320, 0, stream>>>(hid, mol_ids, (float*)d_out, 100000);
}

// Round 12
// 1140.296 us; speedup vs baseline: 1.3062x; 1.3062x over previous
//
#include <hip/hip_runtime.h>

// ---------------------------------------------------------------------------
// MPN (chemprop) on MI355X. bf16 MFMA (16x16x32), fp32 accum.
//   relu(inp + m@W_h) == relu([f_bonds | m] @ [W_i ; W_h])  -> no stored inp.
// R1: XCD-paired decode. R2 de-fuse / R4 direct-frag / R7 small-tile /
//     R9 deferred-sub / R10 wave-private: all REVERTED (counter history in
//     journal). R3 (reg-staged LDS dbuf + counted barrier) was best: 159µs
//     loop GEMM, 1127.8 total, MfmaUtil 15%.
// R11: m97-faithful staging — __builtin_amdgcn_global_load_lds(16B) for A,
//     msg-rows AND B (no VGPR round-trip, no ds_write, no staging regs).
//     Per-lane GLOBAL source carries the XOR-quarter swizzle; LDS stays
//     linear (m173 rule). Combine via LINEARITY: acc += amsg@B + (-msg)@B
//     (sign-flip XOR; removes bfsub chain + one bf16 rounding). Plain
//     __syncthreads 2-barrier loop exactly as m97.
//     (Round 11 bench was an infra failure — resubmitted with __align__(16)
//     on the LDS arrays; otherwise identical.)
// GEMM: block 128M x 160N, wave 64x80 (4x5). LDS 52KB: As/Ams 2x[128][32],
//     Bs 2x[160][32], all source-swizzled for conflict-spread ds_read_b128.
// Workspace (~367 MiB): wih | wto | fbp | amsg | msgA | msgB
// ---------------------------------------------------------------------------

#define DEVFN static __device__ __forceinline__
#define AS1 __attribute__((address_space(1)))
#define AS3 __attribute__((address_space(3)))

typedef __attribute__((ext_vector_type(8))) __bf16 bf16x8;
typedef __attribute__((ext_vector_type(4))) float floatx4;

DEVFN unsigned short f2bf(float f) {
    unsigned int u = __float_as_uint(f);
    u += 0x7FFFu + ((u >> 16) & 1u);   // RNE
    return (unsigned short)(u >> 16);
}
DEVFN float bf2f(unsigned int u) { return __uint_as_float(u << 16); }

// async 16B/lane global->LDS (lds dest: wave-uniform base + lane*16)
DEVFN void gl16(const unsigned short* g, unsigned short* l) {
    __builtin_amdgcn_global_load_lds((const AS1 unsigned int*)g,
                                     (AS3 unsigned int*)l, 16, 0, 0);
}

// ---------------------------------------------------------------------------
__global__ __launch_bounds__(256) void dbg_fill(float* out, int n, float v) {
    int t = blockIdx.x * 256 + threadIdx.x;
    if (t < n) out[t] = v;
}

// Wih[320][480]: k<147 -> W_i[k][n]; 160<=k<460 -> W_h[k-160][n]; else 0
__global__ __launch_bounds__(256) void prep_wih(const float* __restrict__ Wi,
                                                const float* __restrict__ Wh,
                                                unsigned short* __restrict__ Wt) {
    int t = blockIdx.x * 256 + threadIdx.x;
    if (t >= 320 * 480) return;
    int n = t / 480, k = t - n * 480;
    float v = 0.f;
    if (n < 300) {
        if (k < 147) v = Wi[k * 300 + n];
        else if (k >= 160 && k < 460) v = Wh[(k - 160) * 300 + n];
    }
    Wt[t] = f2bf(v);
}

// Wto[320][448]: k<300 -> W_o[133+k][n]; 304<=k<437 -> W_o[k-304][n]; else 0
__global__ __launch_bounds__(256) void prep_wto(const float* __restrict__ Wo,
                                                unsigned short* __restrict__ Wt) {
    int t = blockIdx.x * 256 + threadIdx.x;
    if (t >= 320 * 448) return;
    int n = t / 448, k = t - n * 448;
    float v = 0.f;
    if (n < 300) {
        if (k < 300) v = Wo[(133 + k) * 300 + n];
        else if (k >= 304 && k < 437) v = Wo[(k - 304) * 300 + n];
    }
    Wt[t] = f2bf(v);
}

// f_bonds [200000][147] fp32 -> [200000][160] bf16 padded
__global__ __launch_bounds__(256) void pad_bonds(const float* __restrict__ fb,
                                                 unsigned short* __restrict__ out) {
    int t = blockIdx.x * 256 + threadIdx.x;
    if (t >= 200000 * 20) return;
    int b = t / 20, c = t - b * 20;
    unsigned int o[4];
#pragma unroll
    for (int p = 0; p < 4; ++p) {
        int sc = c * 8 + p * 2;
        float v0 = (sc < 147) ? fb[(size_t)b * 147 + sc] : 0.f;
        float v1 = (sc + 1 < 147) ? fb[(size_t)b * 147 + sc + 1] : 0.f;
        o[p] = (unsigned int)f2bf(v0) | ((unsigned int)f2bf(v1) << 16);
    }
    *(uint4*)(out + (size_t)b * 160 + c * 8) = make_uint4(o[0], o[1], o[2], o[3]);
}

// f_atoms [100000][133] fp32 -> concat cols 304..447
__global__ __launch_bounds__(256) void atoms_concat(const float* __restrict__ fa,
                                                    unsigned short* __restrict__ concat) {
    int t = blockIdx.x * 256 + threadIdx.x;
    if (t >= 100000 * 18) return;
    int a = t / 18, c = t - a * 18;
    unsigned int o[4];
#pragma unroll
    for (int p = 0; p < 4; ++p) {
        int sc = c * 8 + p * 2;
        float v0 = (sc < 133) ? fa[(size_t)a * 133 + sc] : 0.f;
        float v1 = (sc + 1 < 133) ? fa[(size_t)a * 133 + sc + 1] : 0.f;
        o[p] = (unsigned int)f2bf(v0) | ((unsigned int)f2bf(v1) << 16);
    }
    *(uint4*)(concat + (size_t)a * 448 + 304 + c * 8) = make_uint4(o[0], o[1], o[2], o[3]);
}

// a_msg[a] = sum_j msg[a2b[a][j]]
template <int CH>
__global__ __launch_bounds__(256) void gather_sum(const unsigned short* __restrict__ msg,
                                                  const int* __restrict__ a2b,
                                                  unsigned short* __restrict__ out,
                                                  int ostride, int nA) {
    int t = blockIdx.x * 256 + threadIdx.x;
    if (t >= nA * CH) return;
    int a = t / CH, c = t - a * CH;
    float s[8] = {0, 0, 0, 0, 0, 0, 0, 0};
#pragma unroll
    for (int j = 0; j < 6; ++j) {
        int b = a2b[a * 6 + j];
        uint4 v = *(const uint4*)(msg + (size_t)b * 320 + c * 8);
        s[0] += bf2f(v.x & 0xffffu); s[1] += bf2f(v.x >> 16);
        s[2] += bf2f(v.y & 0xffffu); s[3] += bf2f(v.y >> 16);
        s[4] += bf2f(v.z & 0xffffu); s[5] += bf2f(v.z >> 16);
        s[6] += bf2f(v.w & 0xffffu); s[7] += bf2f(v.w >> 16);
    }
    unsigned int o[4];
#pragma unroll
    for (int p = 0; p < 4; ++p)
        o[p] = (unsigned int)f2bf(s[2 * p]) | ((unsigned int)f2bf(s[2 * p + 1]) << 16);
    *(uint4*)(out + (size_t)a * ostride + c * 8) = make_uint4(o[0], o[1], o[2], o[3]);
}

// ---------------------------------------------------------------------------
// m97-style GEMM.  C[M][320] = [A0 | (amsg[b2a] - msg[b2revb])] @ Wt^T
//   All staging via global_load_lds (16B/lane). LDS linear; the XOR-quarter
//   swizzle lives in the per-lane GLOBAL source chunk: LDS[row][c] holds
//   global chunk c^(row&3); reads use chunk quad^(row&3). Involution.
//   As/Ams: [128 rows][32 k-shorts]; slot = r*256+tid -> (row=slot>>2,
//   chunk=slot&3); wave-uniform LDS base = slot&~63. Bs: [160][32],
//   2.5 rounds (u = tid, tid+256, tid+512 for tid<128) — R3's scheme.
//   Combine kts (kt>=KT0): amsg rows -> As, msg rows -> Ams; compute does
//   acc += amsg@B then acc += (-msg)@B (sign-flip XOR, fp32 accumulate).
//   Loop: stage(kt+1 -> buf^1) -> ds_read+MFMA(buf) -> __syncthreads.
// MODE 0: outp[r*320+col] = relu(acc) bf16
// MODE 2: hid[r*300+col]  = relu(acc + bo[col]) fp32  (col<300)
// ---------------------------------------------------------------------------
template <int KT0, int KT1, int MODE, int BSTRIDE>
__global__ __launch_bounds__(256) void gemm_k(const unsigned short* __restrict__ A0,
                                              int a0s,
                                              const unsigned short* __restrict__ amsg,
                                              const unsigned short* __restrict__ msg,
                                              const int* __restrict__ b2a,
                                              const int* __restrict__ b2revb,
                                              const unsigned short* __restrict__ Wt,
                                              unsigned short* __restrict__ outp,
                                              float* __restrict__ hid,
                                              const float* __restrict__ bo, int M) {
    constexpr int KT = KT0 + KT1;
    __shared__ __align__(16) unsigned short As[2 * 4096];                    // [buf][128][32]
    __shared__ __align__(16) unsigned short Bs[2 * 5120];                    // [buf][160][32]
    __shared__ __align__(16) unsigned short Ams[(KT1 > 0) ? 2 * 4096 : 64];  // [buf][128][32]

    const int tid = threadIdx.x;
    const int lane = tid & 63;
    const int wave = tid >> 6;
    const int wm = wave & 1, wn = wave >> 1;
    const int l16 = lane & 15, quad = lane >> 4;

    // ---- XCD-paired m/n decode (bijective incl. tail) ----
    int m0, n0;
    {
        const int bid = blockIdx.x;
        const int MB = (int)(gridDim.x >> 1);
        const int mfull = (MB >> 3) << 3;        // largest mult of 8 <= MB
        const int FULL = mfull << 1;
        int mb, nh;
        if (bid < FULL) {
            nh = (bid >> 3) & 1;
            mb = ((bid >> 4) << 3) + (bid & 7);
        } else {
            const int r = bid - FULL;
            const int rem = MB - mfull;
            nh = (r >= rem) ? 1 : 0;
            mb = mfull + r - nh * rem;
        }
        m0 = mb * 128;
        n0 = nh * 160;
    }

    // ---- staging source pointers (per-lane, chunk-swizzled) ----
    // A rows: slot s = r*256+tid -> row = s>>2 (this thread: rl0 = wave*16 +
    // lane/4 for r=0, rl1 = 64+rl0 for r=1), chunk = lane&3, source chunk =
    // (lane ^ (lane>>2)) & 3.
    const int rl0 = wave * 16 + (lane >> 2);
    const int rl1 = 64 + rl0;
    const int csrc = ((lane ^ (lane >> 2)) & 3) * 8;
    const int gr0 = min(m0 + rl0, M - 1);
    const int gr1 = min(m0 + rl1, M - 1);
    const unsigned short* a00 = A0 + (size_t)gr0 * a0s + csrc;
    const unsigned short* a01 = A0 + (size_t)gr1 * a0s + csrc;
    const unsigned short* am0 = A0;
    const unsigned short* am1 = A0;
    const unsigned short* ms0 = A0;
    const unsigned short* ms1 = A0;
    if (KT1 > 0) {
        am0 = amsg + (size_t)b2a[gr0] * 320 + csrc;
        am1 = amsg + (size_t)b2a[gr1] * 320 + csrc;
        ms0 = msg + (size_t)b2revb[gr0] * 320 + csrc;
        ms1 = msg + (size_t)b2revb[gr1] * 320 + csrc;
    }
    // B slots: u -> row = n0 + (u>>2), source chunk = (u ^ (u>>2)) & 3.
    const int u0 = tid, u1 = tid + 256, u2 = tid + 512;
    const unsigned short* b0 = Wt + (size_t)(n0 + (u0 >> 2)) * BSTRIDE + ((u0 ^ (u0 >> 2)) & 3) * 8;
    const unsigned short* b1 = Wt + (size_t)(n0 + (u1 >> 2)) * BSTRIDE + ((u1 ^ (u1 >> 2)) & 3) * 8;
    const unsigned short* b2 = (tid < 128)
        ? Wt + (size_t)(n0 + (u2 >> 2)) * BSTRIDE + ((u2 ^ (u2 >> 2)) & 3) * 8 : Wt;

    const int aw = wave * 512;   // per-wave LDS slot base (shorts; 1KB)

    // ---- fragment read offsets (shorts; chunk-swizzle inverse) ----
    int aoff[4], boff[5];
#pragma unroll
    for (int tm = 0; tm < 4; ++tm) {
        int row = wm * 64 + tm * 16 + l16;
        aoff[tm] = row * 32 + ((quad ^ row) & 3) * 8;
    }
#pragma unroll
    for (int tn = 0; tn < 5; ++tn) {
        int nl = wn * 80 + tn * 16 + l16;
        boff[tn] = nl * 32 + ((quad ^ nl) & 3) * 8;
    }

    floatx4 acc[4][5];
#pragma unroll
    for (int tm = 0; tm < 4; ++tm)
#pragma unroll
        for (int tn = 0; tn < 5; ++tn) acc[tm][tn] = (floatx4){0.f, 0.f, 0.f, 0.f};

    // ---- async staging of tile kt into buf (then advance sources) ----
    auto stage = [&](int buf, int kt) {
        unsigned short* ab = As + buf * 4096;
        if (kt < KT0) {
            gl16(a00, ab + aw);
            gl16(a01, ab + 2048 + aw);
            if (kt + 1 < KT0) { a00 += 32; a01 += 32; }
        } else {
            gl16(am0, ab + aw);
            gl16(am1, ab + 2048 + aw);
            unsigned short* mb = Ams + buf * 4096;
            gl16(ms0, mb + aw);
            gl16(ms1, mb + 2048 + aw);
            am0 += 32; am1 += 32; ms0 += 32; ms1 += 32;
        }
        unsigned short* bb = Bs + buf * 5120;
        gl16(b0, bb + aw);
        gl16(b1, bb + 2048 + aw);
        if (tid < 128) gl16(b2, bb + 4096 + aw);
        b0 += 32; b1 += 32; b2 += 32;
    };

    auto compute = [&](int buf, int kt) {
        const unsigned short* ab = As + buf * 4096;
        const unsigned short* bb = Bs + buf * 5120;
        bf16x8 av[4], bv[5];
#pragma unroll
        for (int tm = 0; tm < 4; ++tm)
            av[tm] = *(const bf16x8*)(ab + aoff[tm]);
#pragma unroll
        for (int tn = 0; tn < 5; ++tn)
            bv[tn] = *(const bf16x8*)(bb + boff[tn]);
#pragma unroll
        for (int tn = 0; tn < 5; ++tn)
#pragma unroll
            for (int tm = 0; tm < 4; ++tm)
                acc[tm][tn] = __builtin_amdgcn_mfma_f32_16x16x32_bf16(av[tm], bv[tn], acc[tm][tn], 0, 0, 0);
        if (kt >= KT0) {
            const unsigned short* mb = Ams + buf * 4096;
            bf16x8 mv[4];
#pragma unroll
            for (int tm = 0; tm < 4; ++tm) {
                uint4 u = *(const uint4*)(mb + aoff[tm]);
                u.x ^= 0x80008000u; u.y ^= 0x80008000u;
                u.z ^= 0x80008000u; u.w ^= 0x80008000u;
                mv[tm] = __builtin_bit_cast(bf16x8, u);
            }
#pragma unroll
            for (int tn = 0; tn < 5; ++tn)
#pragma unroll
                for (int tm = 0; tm < 4; ++tm)
                    acc[tm][tn] = __builtin_amdgcn_mfma_f32_16x16x32_bf16(mv[tm], bv[tn], acc[tm][tn], 0, 0, 0);
        }
    };

    // ---- m97 main loop ----
    stage(0, 0);
    __syncthreads();
#pragma unroll
    for (int kt = 0; kt < KT; ++kt) {
        const int buf = kt & 1;
        if (kt + 1 < KT) stage(buf ^ 1, kt + 1);
        compute(buf, kt);
        __syncthreads();
    }

    // ---- epilogue ----
    float bias[5];
    if (MODE == 2) {
#pragma unroll
        for (int tn = 0; tn < 5; ++tn) {
            int col = n0 + wn * 80 + tn * 16 + l16;
            bias[tn] = (col < 300) ? bo[col] : 0.f;
        }
    }
#pragma unroll
    for (int tm = 0; tm < 4; ++tm) {
        const int r0 = m0 + wm * 64 + tm * 16 + quad * 4;
#pragma unroll
        for (int tn = 0; tn < 5; ++tn) {
            const int col = n0 + wn * 80 + tn * 16 + l16;
#pragma unroll
            for (int i = 0; i < 4; ++i) {
                int r = r0 + i;
                if (r >= M) continue;
                float c = acc[tm][tn][i];
                if (MODE == 2) {
                    if (col < 300) hid[(size_t)r * 300 + col] = fmaxf(c + bias[tn], 0.f);
                } else {
                    outp[(size_t)r * 320 + col] = f2bf(fmaxf(c, 0.f));
                }
            }
        }
    }
}

// ---------------------------------------------------------------------------
// Per-molecule mean. mol_ids sorted -> binary search row range.
// ---------------------------------------------------------------------------
__global__ __launch_bounds__(320) void mean_k(const float* __restrict__ hid,
                                              const int* __restrict__ mol_ids,
                                              float* __restrict__ out, int nA) {
    int mol = blockIdx.x;
    int lo, hi;
    {
        int l = 0, h = nA;
        while (l < h) { int m = (l + h) >> 1; if (mol_ids[m] < mol) l = m + 1; else h = m; }
        lo = l;
    }
    {
        int l = lo, h = nA;
        while (l < h) { int m = (l + h) >> 1; if (mol_ids[m] < mol + 1) l = m + 1; else h = m; }
        hi = l;
    }
    int col = threadIdx.x;
    if (col >= 300) return;
    float s = 0.f;
    for (int a = lo; a < hi; ++a) s += hid[(size_t)a * 300 + col];
    int cnt = hi - lo;
    out[(size_t)mol * 300 + col] = s / (float)(cnt > 0 ? cnt : 1);
}

// ---------------------------------------------------------------------------
extern "C" void kernel_launch(void* const* d_in, const int* in_sizes, int n_in,
                              void* d_out, int out_size, void* d_ws, size_t ws_size,
                              hipStream_t stream) {
    (void)in_sizes; (void)n_in;
    const float* f_atoms = (const float*)d_in[0];
    const float* f_bonds = (const float*)d_in[1];
    const float* W_i     = (const float*)d_in[2];
    const float* W_h     = (const float*)d_in[3];
    const float* W_o     = (const float*)d_in[4];
    const float* b_o     = (const float*)d_in[5];
    const int*   a2b     = (const int*)d_in[6];
    const int*   b2a     = (const int*)d_in[7];
    const int*   b2revb  = (const int*)d_in[8];
    const int*   mol_ids = (const int*)d_in[9];

    const size_t sz_wih  = 320ull * 480 * 2;
    const size_t sz_wto  = 320ull * 448 * 2;
    const size_t sz_fbp  = 200000ull * 160 * 2;
    const size_t sz_amsg = 100000ull * 320 * 2;
    const size_t sz_msg  = 200000ull * 320 * 2;
    const size_t need = sz_wih + sz_wto + sz_fbp + sz_amsg + 2 * sz_msg;

    if (ws_size < need) {
        dbg_fill<<<(out_size + 255) / 256, 256, 0, stream>>>(
            (float*)d_out, out_size, (float)(ws_size >> 20));
        return;
    }

    char* ws = (char*)d_ws;
    unsigned short* wih  = (unsigned short*)(ws);
    unsigned short* wto  = (unsigned short*)(ws + sz_wih);
    unsigned short* fbp  = (unsigned short*)(ws + sz_wih + sz_wto);
    unsigned short* amsg = (unsigned short*)(ws + sz_wih + sz_wto + sz_fbp);
    unsigned short* msgA = (unsigned short*)(ws + sz_wih + sz_wto + sz_fbp + sz_amsg);
    unsigned short* msgB = (unsigned short*)(ws + sz_wih + sz_wto + sz_fbp + sz_amsg + sz_msg);
    unsigned short* concat = msgA;                     // msgA dead after loop
    float*          hid    = (float*)msgB;             // msgB dead after final gather

    prep_wih<<<600, 256, 0, stream>>>(W_i, W_h, wih);
    prep_wto<<<560, 256, 0, stream>>>(W_o, wto);
    pad_bonds<<<15625, 256, 0, stream>>>(f_bonds, fbp);

    // msgA = relu(f_bonds @ W_i)   (grid = 2*MB, MB = ceil(200000/128) = 1563)
    gemm_k<5, 0, 0, 480><<<dim3(3126), 256, 0, stream>>>(
        fbp, 160, nullptr, nullptr, nullptr, nullptr, wih, msgA, nullptr, nullptr, 200000);

    unsigned short* cur = msgA;
    unsigned short* other = msgB;
    for (int d = 0; d < 3; ++d) {   // DEPTH-1
        gather_sum<40><<<15625, 256, 0, stream>>>(cur, a2b, amsg, 320, 100000);
        gemm_k<5, 10, 0, 480><<<dim3(3126), 256, 0, stream>>>(
            fbp, 160, amsg, cur, b2a, b2revb, wih, other, nullptr, nullptr, 200000);
        unsigned short* t = cur; cur = other; other = t;
    }

    // final gather into concat cols 0..303 (cur == msgB; concat == msgA)
    gather_sum<38><<<14844, 256, 0, stream>>>(cur, a2b, concat, 448, 100000);
    atoms_concat<<<7032, 256, 0, stream>>>(f_atoms, concat);
    // hid = relu(concat @ W_o + b_o)   (MB = ceil(100000/128) = 782)
    gemm_k<14, 0, 2, 448><<<dim3(1564), 256, 0, stream>>>(
        concat, 448, nullptr, nullptr, nullptr, nullptr, wto, nullptr, hid, b_o, 100000);
    mean_k<<<8192, 320, 0, stream>>>(hid, mol_ids, (float*)d_out, 100000);
}